// Round 6
// baseline (292.542 us; speedup 1.0000x reference)
//
#include <hip/hip_runtime.h>

// Problem constants
#define L_SEQ   4096
#define BSZQ    8
#define ROWS    (BSZQ * L_SEQ)      // 32768
#define KC1     512                 // GEMM1 K  (= H)
#define NC1     1024                // GEMM1 out cols (= 2*N interleaved re/im)
#define KC2     1024                // GEMM2 K
#define NC2     512                 // GEMM2 out cols (= H)
#define CHUNK   64
#define NCHUNK  64                  // L_SEQ / CHUNK

typedef __attribute__((ext_vector_type(8))) short bfrag;   // 8 bf16 (4 VGPRs)
typedef __attribute__((ext_vector_type(4))) float ffrag;   // 4 fp32 acc

static __device__ __forceinline__ unsigned short f2bf(float f) {
    union { float f; unsigned int u; } v; v.f = f;
    unsigned int r = v.u + 0x7fffu + ((v.u >> 16) & 1u);   // round-nearest-even
    return (unsigned short)(r >> 16);
}
static __device__ __forceinline__ unsigned int pk2(float a, float b) {
    return (unsigned int)f2bf(a) | ((unsigned int)f2bf(b) << 16);
}
static __device__ __forceinline__ float2 unpk2(unsigned int u) {
    union { unsigned int u; float f; } a, b;
    a.u = u << 16;
    b.u = u & 0xffff0000u;
    return make_float2(a.f, b.f);
}

// async global->LDS, 16B per lane; lds dest = wave-uniform base + lane*16
static __device__ __forceinline__ void async16(const void* g, void* l) {
    __builtin_amdgcn_global_load_lds(
        (const __attribute__((address_space(1))) unsigned int*)g,
        (__attribute__((address_space(3))) unsigned int*)l,
        16, 0, 0);
}

// ---- fused prep: lam + Bt + Dt --------------------------------------------
__global__ __launch_bounds__(256) void prep_all_kernel(
    const float* __restrict__ B, const float* __restrict__ C,
    const float* __restrict__ nu_log, const float* __restrict__ theta_log,
    unsigned short* __restrict__ Bt, unsigned short* __restrict__ Dt,
    float2* __restrict__ lam)
{
    int g = blockIdx.x, tid = threadIdx.x;
    if (g < 2048) {
        int idx = g * 256 + tid;                // 524288 total
        int n2 = idx >> 9, h = idx & 511;
        Bt[idx] = f2bf(B[(size_t)h * 1024 + n2]);
    } else if (g < 4096) {
        int idx = (g - 2048) * 256 + tid;       // 524288 total
        int j = idx >> 10, k = idx & 1023;
        int n = k >> 1, c = k & 1;
        float v = C[((size_t)c * 512 + n) * 512 + j];
        Dt[idx] = f2bf(c ? -v : v);
    } else {
#pragma unroll
        for (int r = 0; r < 2; r++) {
            int n = tid + r * 256;
            float mag = expf(-expf(nu_log[n]));
            float th  = expf(theta_log[n]);
            lam[n] = make_float2(mag * cosf(th), mag * sinf(th));
        }
    }
}

// ========== GEMM1 with fused fp32->bf16 conversion + length mask ============
// bu[r, n2] = sum_k u[r,k] * Bt[n2,k], output packed (re,im) bf16 per complex
// col.  128x128 tile, BK=32, 4 waves (2x2), 2-buffer issue-early staging.
// A path: reg-staged — global_load_dwordx4 fp32 u -> pk2 -> swizzled
// ds_write_b128 (mask folded in).  Replaces the standalone conv_mask kernel.
// B path: global_load_lds with pre-swizzled source (R3-verified).
// Swizzle (both sides): stored 16B chunk sc holds global chunk sc ^ ((r>>1)&3).
// XCD swizzle (col-fast): each XCD owns a contiguous row-tile range -> A
// panels re-read from that XCD's L2 across the 8 col-tiles.
__global__ __launch_bounds__(256, 4) void gemm1_conv(
    const float* __restrict__ U,            // fp32 [32768][512]
    const unsigned short* __restrict__ Bt,  // bf16 [1024][512]
    const int* __restrict__ lengths,
    unsigned int* __restrict__ Cb)          // packed bf16 [32768][512]
{
    __shared__ __align__(16) unsigned short As[2][128 * 32];  // 2 x 8 KB
    __shared__ __align__(16) unsigned short Bs[2][128 * 32];  // 2 x 8 KB

    const int tid  = threadIdx.x;
    const int lane = tid & 63, w = tid >> 6;
    const int q = lane >> 4, m16 = lane & 15;
    const int wr = (w >> 1) * 64, wc = (w & 1) * 64;

    // XCD swizzle: nwg=2048, Q=256; col-fast decode (GY=8)
    const int o = (blockIdx.x & 7) * 256 + (blockIdx.x >> 3);
    const int row0 = (o >> 3) * 128;
    const int col0 = (o & 7) * 128;

    // A conv-staging assignment: thread -> (row, K-half of 16 floats)
    const int ar = tid >> 1;                 // tile row 0..127
    const int ah = tid & 1;                  // K-half
    const int as_ = (ar >> 1) & 3;           // chunk swizzle for this row
    const int grow = row0 + ar;
    const bool keep = (grow & (L_SEQ - 1)) < lengths[grow >> 12];
    const float* pA = U + (size_t)grow * KC1 + ah * 16;

    ffrag acc[4][4];
#pragma unroll
    for (int i = 0; i < 4; i++)
#pragma unroll
        for (int j = 0; j < 4; j++) acc[i][j] = (ffrag)0.f;

    float4 fa[4];

#define LOADA(KT) do {                                                         \
    _Pragma("unroll")                                                          \
    for (int i_ = 0; i_ < 4; i_++)                                             \
        fa[i_] = *(const float4*)(pA + (KT) + i_ * 4);                         \
} while (0)

    // convert fa -> 2 swizzled 16B LDS chunks (global chunks 2*ah, 2*ah+1)
#define CWRITE(BUF) do {                                                       \
    uint4 lo_ = make_uint4(pk2(fa[0].x, fa[0].y), pk2(fa[0].z, fa[0].w),       \
                           pk2(fa[1].x, fa[1].y), pk2(fa[1].z, fa[1].w));      \
    uint4 hi_ = make_uint4(pk2(fa[2].x, fa[2].y), pk2(fa[2].z, fa[2].w),       \
                           pk2(fa[3].x, fa[3].y), pk2(fa[3].z, fa[3].w));      \
    if (!keep) { lo_ = make_uint4(0u,0u,0u,0u); hi_ = make_uint4(0u,0u,0u,0u); } \
    *(uint4*)&BUF[ar * 32 + ((2 * ah)     ^ as_) * 8] = lo_;                   \
    *(uint4*)&BUF[ar * 32 + ((2 * ah + 1) ^ as_) * 8] = hi_;                   \
} while (0)

#define STAGE_B1(TB, KT) do {                                                  \
    _Pragma("unroll")                                                          \
    for (int j_ = 0; j_ < 2; j_++) {                                           \
        int s_ = j_ * 256 + tid;                                               \
        int r_ = s_ >> 2;                                                      \
        int cs_ = (s_ & 3) ^ ((r_ >> 1) & 3);                                  \
        async16(Bt + (size_t)(col0 + r_) * KC1 + (KT) + cs_ * 8,               \
                &TB[(size_t)(j_ * 256 + w * 64) * 8]);                         \
    }                                                                          \
} while (0)

    // prologue: tile 0
    LOADA(0);
    STAGE_B1(Bs[0], 0);
    CWRITE(As[0]);
    __syncthreads();

    int c = 0;
    for (int kt = 0; kt < KC1; kt += 32) {
        const bool nl = (kt + 32 < KC1);
        if (nl) { LOADA(kt + 32); STAGE_B1(Bs[c ^ 1], kt + 32); }
        bfrag a[4], b[4];
#pragma unroll
        for (int ri = 0; ri < 4; ri++) {
            int r_ = wr + ri * 16 + m16;
            a[ri] = *(const bfrag*)&As[c][r_ * 32 + (q ^ ((r_ >> 1) & 3)) * 8];
        }
#pragma unroll
        for (int ci = 0; ci < 4; ci++) {
            int r_ = wc + ci * 16 + m16;
            b[ci] = *(const bfrag*)&Bs[c][r_ * 32 + (q ^ ((r_ >> 1) & 3)) * 8];
        }
#pragma unroll
        for (int ri = 0; ri < 4; ri++)
#pragma unroll
            for (int ci = 0; ci < 4; ci++)
                acc[ri][ci] = __builtin_amdgcn_mfma_f32_16x16x32_bf16(
                    a[ri], b[ci], acc[ri][ci], 0, 0, 0);
        if (nl) CWRITE(As[c ^ 1]);    // As[c^1] last read one barrier ago: safe
        __syncthreads();
        c ^= 1;
    }
#undef LOADA
#undef CWRITE
#undef STAGE_B1

    // bf16 packed epilogue (verified R2/R3): shfl_xor(1) pairs re/im columns
    const int colc0 = (col0 >> 1) + (w & 1) * 32;
#pragma unroll
    for (int ri = 0; ri < 4; ri++)
#pragma unroll
        for (int cp = 0; cp < 2; cp++)
#pragma unroll
            for (int r4 = 0; r4 < 4; r4++) {
                float a0 = acc[ri][cp * 2][r4];
                float a1 = acc[ri][cp * 2 + 1][r4];
                float b0 = __shfl_xor(a0, 1);
                float b1 = __shfl_xor(a1, 1);
                unsigned int uo = (m16 & 1) ? pk2(b1, a1) : pk2(a0, b0);
                int row = row0 + wr + ri * 16 + q * 4 + r4;
                int ccol = (cp * 2 + (m16 & 1)) * 8 + (m16 >> 1);
                Cb[(size_t)row * (NC1 / 2) + colc0 + ccol] = uo;
            }
}

// ============ GEMM2: y = x(packed bf16) @ Dt^T, fp32 out ====================
// 128x128 tile, BK=32, 2-buffer issue-early (R3 structure, best measured) +
// XCD col-fast swizzle. Both operands via global_load_lds w/ source swizzle.
__global__ __launch_bounds__(256, 4) void gemm2_db(
    const unsigned short* __restrict__ A,   // bu as bf16 [32768][1024]
    const unsigned short* __restrict__ Bt,  // Dt [512][1024]
    float* __restrict__ Cf)                 // y [32768][512]
{
    __shared__ __align__(16) unsigned short As[2][128 * 32];  // 2 x 8 KB
    __shared__ __align__(16) unsigned short Bs[2][128 * 32];  // 2 x 8 KB

    const int tid  = threadIdx.x;
    const int lane = tid & 63, w = tid >> 6;
    const int q = lane >> 4, m16 = lane & 15;
    const int wr = (w >> 1) * 64, wc = (w & 1) * 64;

    // XCD swizzle: nwg=1024, Q=128; col-fast decode (GY=4)
    const int o = (blockIdx.x & 7) * 128 + (blockIdx.x >> 3);
    const int row0 = (o >> 2) * 128;
    const int col0 = (o & 3) * 128;

    ffrag acc[4][4];
#pragma unroll
    for (int i = 0; i < 4; i++)
#pragma unroll
        for (int j = 0; j < 4; j++) acc[i][j] = (ffrag)0.f;

#define STAGE_T2(GP, TB, KT, GR0) do {                                         \
    _Pragma("unroll")                                                          \
    for (int j_ = 0; j_ < 2; j_++) {                                           \
        int s_ = j_ * 256 + tid;                                               \
        int r_ = s_ >> 2;                                                      \
        int cs_ = (s_ & 3) ^ ((r_ >> 1) & 3);                                  \
        async16(GP + (size_t)((GR0) + r_) * KC2 + (KT) + cs_ * 8,              \
                &TB[(size_t)(j_ * 256 + w * 64) * 8]);                         \
    }                                                                          \
} while (0)

    STAGE_T2(A,  As[0], 0, row0);
    STAGE_T2(Bt, Bs[0], 0, col0);
    __syncthreads();

    int c = 0;
    for (int kt = 0; kt < KC2; kt += 32) {
        if (kt + 32 < KC2) {
            STAGE_T2(A,  As[c ^ 1], kt + 32, row0);
            STAGE_T2(Bt, Bs[c ^ 1], kt + 32, col0);
        }
        bfrag a[4], b[4];
#pragma unroll
        for (int ri = 0; ri < 4; ri++) {
            int r_ = wr + ri * 16 + m16;
            a[ri] = *(const bfrag*)&As[c][r_ * 32 + (q ^ ((r_ >> 1) & 3)) * 8];
        }
#pragma unroll
        for (int ci = 0; ci < 4; ci++) {
            int r_ = wc + ci * 16 + m16;
            b[ci] = *(const bfrag*)&Bs[c][r_ * 32 + (q ^ ((r_ >> 1) & 3)) * 8];
        }
#pragma unroll
        for (int ri = 0; ri < 4; ri++)
#pragma unroll
            for (int ci = 0; ci < 4; ci++)
                acc[ri][ci] = __builtin_amdgcn_mfma_f32_16x16x32_bf16(
                    a[ri], b[ci], acc[ri][ci], 0, 0, 0);
        __syncthreads();
        c ^= 1;
    }
#undef STAGE_T2

    // fp32 dword scatter: per (ri,r4,ci) 16 lanes = one full 64B line.
#pragma unroll
    for (int ri = 0; ri < 4; ri++)
#pragma unroll
        for (int r4 = 0; r4 < 4; r4++) {
            int row = row0 + wr + ri * 16 + q * 4 + r4;
#pragma unroll
            for (int ci = 0; ci < 4; ci++) {
                int col = col0 + wc + ci * 16 + m16;
                Cf[(size_t)row * NC2 + col] = acc[ri][ci][r4];
            }
        }
}

// ------- scan phase 1: chunk-final states (vectorized: uint2 per lane) ------
// 256 threads; thread t owns n-pair {2t, 2t+1} (both in same direction half).
__global__ __launch_bounds__(256) void scan_states_kernel(
    const unsigned int* __restrict__ bu, const float2* __restrict__ lam,
    float2* __restrict__ states)
{
    int t = threadIdx.x;
    int b = blockIdx.x >> 6;
    int c = blockIdx.x & 63;
    float4 lm = *(const float4*)&lam[2 * t];   // (l0.re,l0.im,l1.re,l1.im)
    float x0r = 0.f, x0i = 0.f, x1r = 0.f, x1i = 0.f;
    bool fwd = (t < 128);
    int l0 = fwd ? (c * CHUNK) : (c * CHUNK + CHUNK - 1);
    const unsigned int* p = bu + ((size_t)b * L_SEQ + l0) * 512 + 2 * t;
    ptrdiff_t step = fwd ? 512 : -512;
#pragma unroll 8
    for (int i = 0; i < CHUNK; i++) {
        uint2 v = *(const uint2*)p;
        float2 v0 = unpk2(v.x), v1 = unpk2(v.y);
        float n0r = lm.x * x0r - lm.y * x0i + v0.x;
        float n0i = lm.x * x0i + lm.y * x0r + v0.y;
        float n1r = lm.z * x1r - lm.w * x1i + v1.x;
        float n1i = lm.z * x1i + lm.w * x1r + v1.y;
        x0r = n0r; x0i = n0i; x1r = n1r; x1i = n1i;
        p += step;
    }
    *(float4*)&states[((size_t)b * NCHUNK + c) * 512 + 2 * t] =
        make_float4(x0r, x0i, x1r, x1i);
}

// ---------------- scan phase 2: combine chunk states -> exclusive carries ---
__global__ __launch_bounds__(512) void scan_combine_kernel(
    const float2* __restrict__ states, float2* __restrict__ carries,
    const float2* __restrict__ lam)
{
    int n = threadIdx.x;
    int b = blockIdx.x;
    float2 lm = lam[n];
    float ar = lm.x, ai = lm.y;          // lam^64 by 6 squarings
#pragma unroll
    for (int i = 0; i < 6; i++) {
        float nr = ar * ar - ai * ai;
        ai = 2.f * ar * ai;
        ar = nr;
    }
    float cr = 0.f, ci = 0.f;
    bool fwd = (n < 256);
    for (int g = 0; g < 8; g++) {
        float2 s[8];
#pragma unroll
        for (int k = 0; k < 8; k++) {
            int c = fwd ? (g * 8 + k) : (63 - (g * 8 + k));
            s[k] = states[((size_t)b * NCHUNK + c) * 512 + n];
        }
#pragma unroll
        for (int k = 0; k < 8; k++) {
            int c = fwd ? (g * 8 + k) : (63 - (g * 8 + k));
            carries[((size_t)b * NCHUNK + c) * 512 + n] = make_float2(cr, ci);
            float nr = ar * cr - ai * ci + s[k].x;
            float ni = ar * ci + ai * cr + s[k].y;
            cr = nr; ci = ni;
        }
    }
}

// -------- scan phase 3: re-scan seeded with carry + mask (uint2/lane) -------
__global__ __launch_bounds__(256) void scan_apply_kernel(
    unsigned int* __restrict__ bu, const float2* __restrict__ carries,
    const float2* __restrict__ lam, const int* __restrict__ lengths)
{
    int t = threadIdx.x;
    int b = blockIdx.x >> 6;
    int c = blockIdx.x & 63;
    int len = lengths[b];
    float4 lm = *(const float4*)&lam[2 * t];
    float4 cy = *(const float4*)&carries[((size_t)b * NCHUNK + c) * 512 + 2 * t];
    bool fwd = (t < 128);
    int l0 = fwd ? (c * CHUNK) : (c * CHUNK + CHUNK - 1);
    int dl = fwd ? 1 : -1;
    unsigned int* p = bu + ((size_t)b * L_SEQ + l0) * 512 + 2 * t;
    ptrdiff_t step = fwd ? 512 : -512;
    float x0r = cy.x, x0i = cy.y, x1r = cy.z, x1i = cy.w;
    int l = l0;
#pragma unroll 8
    for (int i = 0; i < CHUNK; i++) {
        uint2 v = *(const uint2*)p;
        float2 v0 = unpk2(v.x), v1 = unpk2(v.y);
        float n0r = lm.x * x0r - lm.y * x0i + v0.x;
        float n0i = lm.x * x0i + lm.y * x0r + v0.y;
        float n1r = lm.z * x1r - lm.w * x1i + v1.x;
        float n1i = lm.z * x1i + lm.w * x1r + v1.y;
        x0r = n0r; x0i = n0i; x1r = n1r; x1i = n1i;
        uint2 o2;
        o2.x = (l >= len) ? 0u : pk2(x0r, x0i);
        o2.y = (l >= len) ? 0u : pk2(x1r, x1i);
        *(uint2*)p = o2;
        p += step; l += dl;
    }
}

// ---------------- launch ----------------------------------------------------
extern "C" void kernel_launch(void* const* d_in, const int* in_sizes, int n_in,
                              void* d_out, int out_size, void* d_ws, size_t ws_size,
                              hipStream_t stream)
{
    const float* u        = (const float*)d_in[0];   // (8,4096,512)
    const int*   lengths  = (const int*)  d_in[1];   // (8,)
    const float* nu_log   = (const float*)d_in[2];   // (512,)
    const float* theta_log= (const float*)d_in[3];   // (512,)
    const float* B        = (const float*)d_in[4];   // (512,512,2) == (512 x 1024)
    const float* C        = (const float*)d_in[5];   // (2,512,512)
    float* y = (float*)d_out;                        // (8,4096,512)

    char* wp = (char*)d_ws;
    float2* lam     = (float2*)wp;  wp += 4096;
    float2* states  = (float2*)wp;  wp += (size_t)BSZQ * NCHUNK * 512 * 8;  // 2 MB
    float2* carries = (float2*)wp;  wp += (size_t)BSZQ * NCHUNK * 512 * 8;  // 2 MB
    unsigned int* bu = (unsigned int*)wp; wp += (size_t)ROWS * 512 * 4;     // 64 MB packed bf16
    unsigned short* Bt = (unsigned short*)wp; wp += (size_t)NC1 * KC1 * 2;  // 1 MB
    unsigned short* Dt = (unsigned short*)wp; wp += (size_t)NC2 * KC2 * 2;  // 1 MB

    prep_all_kernel<<<4097, 256, 0, stream>>>(B, C, nu_log, theta_log, Bt, Dt, lam);

    // GEMM1 (+ fused fp32->bf16 conversion and length mask)
    gemm1_conv<<<(ROWS / 128) * (NC1 / 128), 256, 0, stream>>>(
        u, Bt, lengths, bu);

    scan_states_kernel<<<BSZQ * NCHUNK, 256, 0, stream>>>(bu, lam, states);
    scan_combine_kernel<<<BSZQ, 512, 0, stream>>>(states, carries, lam);
    scan_apply_kernel<<<BSZQ * NCHUNK, 256, 0, stream>>>(bu, carries, lam, lengths);

    // GEMM2: y = bu(=x, packed bf16) @ Dt^T, fp32 out
    gemm2_db<<<(ROWS / 128) * (NC2 / 128), 256, 0, stream>>>(
        (const unsigned short*)bu, Dt, y);
}

// Round 7
// 273.608 us; speedup vs baseline: 1.0692x; 1.0692x over previous
//
#include <hip/hip_runtime.h>

// Problem constants
#define L_SEQ   4096
#define BSZQ    8
#define ROWS    (BSZQ * L_SEQ)      // 32768
#define KC1     512                 // GEMM1 K  (= H)
#define NC1     1024                // GEMM1 out cols (= 2*N interleaved re/im)
#define KC2     1024                // GEMM2 K
#define NC2     512                 // GEMM2 out cols (= H)
#define CHUNK   64
#define NCHUNK  64                  // L_SEQ / CHUNK

typedef __attribute__((ext_vector_type(8))) short bfrag;   // 8 bf16 (4 VGPRs)
typedef __attribute__((ext_vector_type(4))) float ffrag;   // 4 fp32 acc

static __device__ __forceinline__ unsigned short f2bf(float f) {
    union { float f; unsigned int u; } v; v.f = f;
    unsigned int r = v.u + 0x7fffu + ((v.u >> 16) & 1u);   // round-nearest-even
    return (unsigned short)(r >> 16);
}
static __device__ __forceinline__ unsigned int pk2(float a, float b) {
    return (unsigned int)f2bf(a) | ((unsigned int)f2bf(b) << 16);
}
static __device__ __forceinline__ float2 unpk2(unsigned int u) {
    union { unsigned int u; float f; } a, b;
    a.u = u << 16;
    b.u = u & 0xffff0000u;
    return make_float2(a.f, b.f);
}

// async global->LDS, 16B per lane; lds dest = wave-uniform base + lane*16
static __device__ __forceinline__ void async16(const void* g, void* l) {
    __builtin_amdgcn_global_load_lds(
        (const __attribute__((address_space(1))) unsigned int*)g,
        (__attribute__((address_space(3))) unsigned int*)l,
        16, 0, 0);
}

// ---- fused prep: lam + Bt + Dt --------------------------------------------
__global__ __launch_bounds__(256) void prep_all_kernel(
    const float* __restrict__ B, const float* __restrict__ C,
    const float* __restrict__ nu_log, const float* __restrict__ theta_log,
    unsigned short* __restrict__ Bt, unsigned short* __restrict__ Dt,
    float2* __restrict__ lam)
{
    int g = blockIdx.x, tid = threadIdx.x;
    if (g < 2048) {
        int idx = g * 256 + tid;                // 524288 total
        int n2 = idx >> 9, h = idx & 511;
        Bt[idx] = f2bf(B[(size_t)h * 1024 + n2]);
    } else if (g < 4096) {
        int idx = (g - 2048) * 256 + tid;       // 524288 total
        int j = idx >> 10, k = idx & 1023;
        int n = k >> 1, c = k & 1;
        float v = C[((size_t)c * 512 + n) * 512 + j];
        Dt[idx] = f2bf(c ? -v : v);
    } else {
#pragma unroll
        for (int r = 0; r < 2; r++) {
            int n = tid + r * 256;
            float mag = expf(-expf(nu_log[n]));
            float th  = expf(theta_log[n]);
            lam[n] = make_float2(mag * cosf(th), mag * sinf(th));
        }
    }
}

// ------------- u (fp32) -> ub (bf16) with length mask folded in -------------
__global__ __launch_bounds__(256) void conv_mask_kernel(
    const float* __restrict__ u, const int* __restrict__ lengths,
    unsigned short* __restrict__ ub)
{
    int idx = blockIdx.x * 256 + threadIdx.x;   // 2,097,152 total (x8 elems)
    int row = idx >> 6;                         // flat row (b*L + l)
    int l = row & (L_SEQ - 1), b = row >> 12;
    bool keep = (l < lengths[b]);
    union { unsigned int s[4]; float4 f; } o;
    if (keep) {
        const float4 a = *(const float4*)(u + (size_t)idx * 8);
        const float4 c = *(const float4*)(u + (size_t)idx * 8 + 4);
        o.s[0] = pk2(a.x, a.y); o.s[1] = pk2(a.z, a.w);
        o.s[2] = pk2(c.x, c.y); o.s[3] = pk2(c.z, c.w);
    } else {
        o.s[0] = o.s[1] = o.s[2] = o.s[3] = 0u;
    }
    *(float4*)(ub + (size_t)idx * 8) = o.f;
}

// ============ 128x128 BK=32 double-buffered issue-early GEMM ================
// R3-verified structure (53.1-53.6 us per dispatch): 4 waves (2x2), 64x64 per
// wave, 32 KB LDS -> 4 blocks/CU; issue-early staging + single __syncthreads
// per K-step; both-sides XOR swizzle (zero bank conflicts measured).
template<int KD, int ND, bool BF16OUT>
__global__ __launch_bounds__(256, 4) void gemm_db(
    const unsigned short* __restrict__ A,   // row-major [., KD] bf16
    const unsigned short* __restrict__ Bt,  // row-major [ND, KD] bf16
    void* __restrict__ Co)
{
    __shared__ __align__(16) unsigned short As[2][128 * 32];  // 2 x 8 KB
    __shared__ __align__(16) unsigned short Bs[2][128 * 32];  // 2 x 8 KB

    const int tid  = threadIdx.x;
    const int lane = tid & 63, w = tid >> 6;
    const int q = lane >> 4, m16 = lane & 15;
    const int wr = (w >> 1) * 64, wc = (w & 1) * 64;
    const int row0 = blockIdx.x * 128;
    const int col0 = blockIdx.y * 128;

    ffrag acc[4][4];
#pragma unroll
    for (int i = 0; i < 4; i++)
#pragma unroll
        for (int j = 0; j < 4; j++) acc[i][j] = (ffrag)0.f;

    // Stage one 128x32 bf16 tile (8 KB = 512 x 16B slots) at K-offset KT.
#define STAGE_T(GP, TB, KT, GR0) do {                                          \
    _Pragma("unroll")                                                          \
    for (int j_ = 0; j_ < 2; j_++) {                                           \
        int s_ = j_ * 256 + tid;                                               \
        int r_ = s_ >> 2;                                                      \
        int cs_ = (s_ & 3) ^ ((r_ >> 1) & 3);                                  \
        async16(GP + (size_t)((GR0) + r_) * KD + (KT) + cs_ * 8,               \
                &TB[(size_t)(j_ * 256 + w * 64) * 8]);                         \
    }                                                                          \
} while (0)

    // prologue
    STAGE_T(A,  As[0], 0, row0);
    STAGE_T(Bt, Bs[0], 0, col0);
    __syncthreads();

    int c = 0;
    for (int kt = 0; kt < KD; kt += 32) {
        if (kt + 32 < KD) {                      // issue-early next tile
            STAGE_T(A,  As[c ^ 1], kt + 32, row0);
            STAGE_T(Bt, Bs[c ^ 1], kt + 32, col0);
        }
        bfrag a[4], b[4];
#pragma unroll
        for (int ri = 0; ri < 4; ri++) {
            int r_ = wr + ri * 16 + m16;
            a[ri] = *(const bfrag*)&As[c][r_ * 32 + (q ^ ((r_ >> 1) & 3)) * 8];
        }
#pragma unroll
        for (int ci = 0; ci < 4; ci++) {
            int r_ = wc + ci * 16 + m16;
            b[ci] = *(const bfrag*)&Bs[c][r_ * 32 + (q ^ ((r_ >> 1) & 3)) * 8];
        }
#pragma unroll
        for (int ri = 0; ri < 4; ri++)
#pragma unroll
            for (int ci = 0; ci < 4; ci++)
                acc[ri][ci] = __builtin_amdgcn_mfma_f32_16x16x32_bf16(
                    a[ri], b[ci], acc[ri][ci], 0, 0, 0);
        __syncthreads();        // drains staged loads; loads flew over compute
        c ^= 1;
    }
#undef STAGE_T

    if (BF16OUT) {
        // In-register re/im pairing (verified R2/R3): shfl_xor(1) pairs cols.
        unsigned int* Cb = (unsigned int*)Co;
        const int colc0 = (col0 >> 1) + (w & 1) * 32;
#pragma unroll
        for (int ri = 0; ri < 4; ri++)
#pragma unroll
            for (int cp = 0; cp < 2; cp++)
#pragma unroll
                for (int r4 = 0; r4 < 4; r4++) {
                    float a0 = acc[ri][cp * 2][r4];
                    float a1 = acc[ri][cp * 2 + 1][r4];
                    float b0 = __shfl_xor(a0, 1);
                    float b1 = __shfl_xor(a1, 1);
                    unsigned int uo = (m16 & 1) ? pk2(b1, a1) : pk2(a0, b0);
                    int row = row0 + wr + ri * 16 + q * 4 + r4;
                    int ccol = (cp * 2 + (m16 & 1)) * 8 + (m16 >> 1);
                    Cb[(size_t)row * (ND / 2) + colc0 + ccol] = uo;
                }
    } else {
        // fp32 dword scatter: per (ri,r4,ci) 16 lanes = one full 64B line.
        float* Cf = (float*)Co;
#pragma unroll
        for (int ri = 0; ri < 4; ri++)
#pragma unroll
            for (int r4 = 0; r4 < 4; r4++) {
                int row = row0 + wr + ri * 16 + q * 4 + r4;
#pragma unroll
                for (int ci = 0; ci < 4; ci++) {
                    int col = col0 + wc + ci * 16 + m16;
                    Cf[(size_t)row * ND + col] = acc[ri][ci][r4];
                }
            }
    }
}

// ------- scan phase 1: chunk-final states (uint2 per lane, R6-verified) -----
__global__ __launch_bounds__(256) void scan_states_kernel(
    const unsigned int* __restrict__ bu, const float2* __restrict__ lam,
    float2* __restrict__ states)
{
    int t = threadIdx.x;
    int b = blockIdx.x >> 6;
    int c = blockIdx.x & 63;
    float4 lm = *(const float4*)&lam[2 * t];   // (l0.re,l0.im,l1.re,l1.im)
    float x0r = 0.f, x0i = 0.f, x1r = 0.f, x1i = 0.f;
    bool fwd = (t < 128);
    int l0 = fwd ? (c * CHUNK) : (c * CHUNK + CHUNK - 1);
    const unsigned int* p = bu + ((size_t)b * L_SEQ + l0) * 512 + 2 * t;
    ptrdiff_t step = fwd ? 512 : -512;
#pragma unroll 8
    for (int i = 0; i < CHUNK; i++) {
        uint2 v = *(const uint2*)p;
        float2 v0 = unpk2(v.x), v1 = unpk2(v.y);
        float n0r = lm.x * x0r - lm.y * x0i + v0.x;
        float n0i = lm.x * x0i + lm.y * x0r + v0.y;
        float n1r = lm.z * x1r - lm.w * x1i + v1.x;
        float n1i = lm.z * x1i + lm.w * x1r + v1.y;
        x0r = n0r; x0i = n0i; x1r = n1r; x1i = n1i;
        p += step;
    }
    *(float4*)&states[((size_t)b * NCHUNK + c) * 512 + 2 * t] =
        make_float4(x0r, x0i, x1r, x1i);
}

// ---- scan phase 2+3 merged: per-block carry recompute + rescan + mask ------
// Each (b,c) block derives its own exclusive carry from the 2 MB L2-resident
// states (group-of-8 preload, chunks processed in direction order via a
// wave-uniform guard), then rescans its chunk in place. Replaces the 8-block
// scan_combine kernel + the carries round-trip.
__global__ __launch_bounds__(256) void scan_fix_apply_kernel(
    unsigned int* __restrict__ bu, const float2* __restrict__ states,
    const float2* __restrict__ lam, const int* __restrict__ lengths)
{
    int t = threadIdx.x;
    int b = blockIdx.x >> 6;
    int c = blockIdx.x & 63;
    int len = lengths[b];
    bool fwd = (t < 128);
    float4 lm = *(const float4*)&lam[2 * t];

    // lam^64 per complex component (6 squarings)
    float a0r = lm.x, a0i = lm.y, a1r = lm.z, a1i = lm.w;
#pragma unroll
    for (int i = 0; i < 6; i++) {
        float n0r = a0r * a0r - a0i * a0i; a0i = 2.f * a0r * a0i; a0r = n0r;
        float n1r = a1r * a1r - a1i * a1i; a1i = 2.f * a1r * a1i; a1r = n1r;
    }

    // exclusive carry for chunk c: fwd processes 0..c-1 ascending; bwd
    // processes 63..c+1 descending. Loop covers all 64 in direction order,
    // guarded updates keep exactly the needed prefix (guard is wave-uniform).
    float c0r = 0.f, c0i = 0.f, c1r = 0.f, c1i = 0.f;
    for (int g = 0; g < 8; ++g) {
        float4 s[8];
#pragma unroll
        for (int k = 0; k < 8; ++k) {
            int cc = fwd ? (g * 8 + k) : (63 - (g * 8 + k));
            s[k] = *(const float4*)&states[((size_t)b * NCHUNK + cc) * 512 + 2 * t];
        }
#pragma unroll
        for (int k = 0; k < 8; ++k) {
            int cc = fwd ? (g * 8 + k) : (63 - (g * 8 + k));
            bool use = fwd ? (cc < c) : (cc > c);
            if (use) {
                float n0r = a0r * c0r - a0i * c0i + s[k].x;
                float n0i = a0r * c0i + a0i * c0r + s[k].y;
                float n1r = a1r * c1r - a1i * c1i + s[k].z;
                float n1i = a1r * c1i + a1i * c1r + s[k].w;
                c0r = n0r; c0i = n0i; c1r = n1r; c1i = n1i;
            }
        }
    }

    // rescan chunk seeded with carry, mask, write back (R6-verified body)
    int l0 = fwd ? (c * CHUNK) : (c * CHUNK + CHUNK - 1);
    int dl = fwd ? 1 : -1;
    unsigned int* p = bu + ((size_t)b * L_SEQ + l0) * 512 + 2 * t;
    ptrdiff_t step = fwd ? 512 : -512;
    float x0r = c0r, x0i = c0i, x1r = c1r, x1i = c1i;
    int l = l0;
#pragma unroll 8
    for (int i = 0; i < CHUNK; i++) {
        uint2 v = *(const uint2*)p;
        float2 v0 = unpk2(v.x), v1 = unpk2(v.y);
        float n0r = lm.x * x0r - lm.y * x0i + v0.x;
        float n0i = lm.x * x0i + lm.y * x0r + v0.y;
        float n1r = lm.z * x1r - lm.w * x1i + v1.x;
        float n1i = lm.z * x1i + lm.w * x1r + v1.y;
        x0r = n0r; x0i = n0i; x1r = n1r; x1i = n1i;
        uint2 o2;
        o2.x = (l >= len) ? 0u : pk2(x0r, x0i);
        o2.y = (l >= len) ? 0u : pk2(x1r, x1i);
        *(uint2*)p = o2;
        p += step; l += dl;
    }
}

// ---------------- launch ----------------------------------------------------
extern "C" void kernel_launch(void* const* d_in, const int* in_sizes, int n_in,
                              void* d_out, int out_size, void* d_ws, size_t ws_size,
                              hipStream_t stream)
{
    const float* u        = (const float*)d_in[0];   // (8,4096,512)
    const int*   lengths  = (const int*)  d_in[1];   // (8,)
    const float* nu_log   = (const float*)d_in[2];   // (512,)
    const float* theta_log= (const float*)d_in[3];   // (512,)
    const float* B        = (const float*)d_in[4];   // (512,512,2) == (512 x 1024)
    const float* C        = (const float*)d_in[5];   // (2,512,512)
    float* y = (float*)d_out;                        // (8,4096,512)

    char* wp = (char*)d_ws;
    float2* lam     = (float2*)wp;  wp += 4096;
    float2* states  = (float2*)wp;  wp += (size_t)BSZQ * NCHUNK * 512 * 8;  // 2 MB
    unsigned int* bu = (unsigned int*)wp; wp += (size_t)ROWS * 512 * 4;     // 64 MB packed bf16
    unsigned short* ub = (unsigned short*)wp; wp += (size_t)ROWS * 512 * 2; // 32 MB
    unsigned short* Bt = (unsigned short*)wp; wp += (size_t)NC1 * KC1 * 2;  // 1 MB
    unsigned short* Dt = (unsigned short*)wp; wp += (size_t)NC2 * KC2 * 2;  // 1 MB

    prep_all_kernel<<<4097, 256, 0, stream>>>(B, C, nu_log, theta_log, Bt, Dt, lam);
    conv_mask_kernel<<<8192, 256, 0, stream>>>(u, lengths, ub);

    // GEMM1: bu(packed bf16) = ub @ Bt^T  (mask folded into ub)
    {
        dim3 grid(ROWS / 128, NC1 / 128);   // (256, 8)
        gemm_db<KC1, NC1, true><<<grid, 256, 0, stream>>>(ub, Bt, bu);
    }

    scan_states_kernel<<<BSZQ * NCHUNK, 256, 0, stream>>>(bu, lam, states);
    scan_fix_apply_kernel<<<BSZQ * NCHUNK, 256, 0, stream>>>(bu, states, lam, lengths);

    // GEMM2: y = bu(=x, packed bf16) @ Dt^T, fp32 out
    {
        dim3 grid(ROWS / 128, NC2 / 128);   // (256, 4)
        gemm_db<KC2, NC2, false><<<grid, 256, 0, stream>>>(
            (const unsigned short*)bu, Dt, y);
    }
}

// Round 9
// 263.142 us; speedup vs baseline: 1.1117x; 1.0398x over previous
//
#include <hip/hip_runtime.h>

// Problem constants
#define L_SEQ   4096
#define BSZQ    8
#define ROWS    (BSZQ * L_SEQ)      // 32768
#define KC1     512                 // GEMM1 K  (= H)
#define NC1     1024                // GEMM1 out cols (= 2*N interleaved re/im)
#define KC2     1024                // GEMM2 K
#define NC2     512                 // GEMM2 out cols (= H)
#define CHUNK   64
#define NCHUNK  64                  // L_SEQ / CHUNK

typedef __attribute__((ext_vector_type(8))) short bfrag;   // 8 bf16 (4 VGPRs)
typedef __attribute__((ext_vector_type(4))) float ffrag;   // 4 fp32 acc

static __device__ __forceinline__ unsigned short f2bf(float f) {
    union { float f; unsigned int u; } v; v.f = f;
    unsigned int r = v.u + 0x7fffu + ((v.u >> 16) & 1u);   // round-nearest-even
    return (unsigned short)(r >> 16);
}
static __device__ __forceinline__ unsigned int pk2(float a, float b) {
    return (unsigned int)f2bf(a) | ((unsigned int)f2bf(b) << 16);
}
static __device__ __forceinline__ float2 unpk2(unsigned int u) {
    union { unsigned int u; float f; } a, b;
    a.u = u << 16;
    b.u = u & 0xffff0000u;
    return make_float2(a.f, b.f);
}

// async global->LDS, 16B per lane; lds dest = wave-uniform base + lane*16
static __device__ __forceinline__ void async16(const void* g, void* l) {
    __builtin_amdgcn_global_load_lds(
        (const __attribute__((address_space(1))) unsigned int*)g,
        (__attribute__((address_space(3))) unsigned int*)l,
        16, 0, 0);
}

// ---- fused prep + conv: conv_mask | Bt | Dt | lam (disjoint elementwise) ---
// blocks 0..8191: ub = bf16(u) with length mask (conv_mask body, R2-verified)
// blocks 8192..10239: Bt[n2][h] = bf16(B[h][n2])
// blocks 10240..12287: Dt[j][2n+c] = bf16(+/- C[c][n][j])
// block 12288: lam
__global__ __launch_bounds__(256) void prep_conv_kernel(
    const float* __restrict__ u, const int* __restrict__ lengths,
    const float* __restrict__ B, const float* __restrict__ C,
    const float* __restrict__ nu_log, const float* __restrict__ theta_log,
    unsigned short* __restrict__ ub, unsigned short* __restrict__ Bt,
    unsigned short* __restrict__ Dt, float2* __restrict__ lam)
{
    int g = blockIdx.x, tid = threadIdx.x;
    if (g < 8192) {
        int idx = g * 256 + tid;                // 2,097,152 total (x8 elems)
        int row = idx >> 6;                     // flat row (b*L + l)
        int l = row & (L_SEQ - 1), b = row >> 12;
        bool keep = (l < lengths[b]);
        union { unsigned int s[4]; float4 f; } o;
        if (keep) {
            const float4 a = *(const float4*)(u + (size_t)idx * 8);
            const float4 c = *(const float4*)(u + (size_t)idx * 8 + 4);
            o.s[0] = pk2(a.x, a.y); o.s[1] = pk2(a.z, a.w);
            o.s[2] = pk2(c.x, c.y); o.s[3] = pk2(c.z, c.w);
        } else {
            o.s[0] = o.s[1] = o.s[2] = o.s[3] = 0u;
        }
        *(float4*)(ub + (size_t)idx * 8) = o.f;
    } else if (g < 10240) {
        int idx = (g - 8192) * 256 + tid;       // 524288 total
        int n2 = idx >> 9, h = idx & 511;
        Bt[idx] = f2bf(B[(size_t)h * 1024 + n2]);
    } else if (g < 12288) {
        int idx = (g - 10240) * 256 + tid;      // 524288 total
        int j = idx >> 10, k = idx & 1023;
        int n = k >> 1, c = k & 1;
        float v = C[((size_t)c * 512 + n) * 512 + j];
        Dt[idx] = f2bf(c ? -v : v);
    } else {
#pragma unroll
        for (int r = 0; r < 2; r++) {
            int n = tid + r * 256;
            float mag = expf(-expf(nu_log[n]));
            float th  = expf(theta_log[n]);
            lam[n] = make_float2(mag * cosf(th), mag * sinf(th));
        }
    }
}

// ============ 128x128 BK=32 double-buffered issue-early GEMM ================
// R3/R7-verified structure (53-55 us per dispatch): 4 waves (2x2), 64x64 per
// wave, 32 KB LDS -> 4 blocks/CU; issue-early staging + single __syncthreads
// per K-step; both-sides XOR swizzle (zero bank conflicts measured).
template<int KD, int ND, bool BF16OUT>
__global__ __launch_bounds__(256, 4) void gemm_db(
    const unsigned short* __restrict__ A,   // row-major [., KD] bf16
    const unsigned short* __restrict__ Bt,  // row-major [ND, KD] bf16
    void* __restrict__ Co)
{
    __shared__ __align__(16) unsigned short As[2][128 * 32];  // 2 x 8 KB
    __shared__ __align__(16) unsigned short Bs[2][128 * 32];  // 2 x 8 KB

    const int tid  = threadIdx.x;
    const int lane = tid & 63, w = tid >> 6;
    const int q = lane >> 4, m16 = lane & 15;
    const int wr = (w >> 1) * 64, wc = (w & 1) * 64;
    const int row0 = blockIdx.x * 128;
    const int col0 = blockIdx.y * 128;

    ffrag acc[4][4];
#pragma unroll
    for (int i = 0; i < 4; i++)
#pragma unroll
        for (int j = 0; j < 4; j++) acc[i][j] = (ffrag)0.f;

    // Stage one 128x32 bf16 tile (8 KB = 512 x 16B slots) at K-offset KT.
#define STAGE_T(GP, TB, KT, GR0) do {                                          \
    _Pragma("unroll")                                                          \
    for (int j_ = 0; j_ < 2; j_++) {                                           \
        int s_ = j_ * 256 + tid;                                               \
        int r_ = s_ >> 2;                                                      \
        int cs_ = (s_ & 3) ^ ((r_ >> 1) & 3);                                  \
        async16(GP + (size_t)((GR0) + r_) * KD + (KT) + cs_ * 8,               \
                &TB[(size_t)(j_ * 256 + w * 64) * 8]);                         \
    }                                                                          \
} while (0)

    // prologue
    STAGE_T(A,  As[0], 0, row0);
    STAGE_T(Bt, Bs[0], 0, col0);
    __syncthreads();

    int c = 0;
    for (int kt = 0; kt < KD; kt += 32) {
        if (kt + 32 < KD) {                      // issue-early next tile
            STAGE_T(A,  As[c ^ 1], kt + 32, row0);
            STAGE_T(Bt, Bs[c ^ 1], kt + 32, col0);
        }
        bfrag a[4], b[4];
#pragma unroll
        for (int ri = 0; ri < 4; ri++) {
            int r_ = wr + ri * 16 + m16;
            a[ri] = *(const bfrag*)&As[c][r_ * 32 + (q ^ ((r_ >> 1) & 3)) * 8];
        }
#pragma unroll
        for (int ci = 0; ci < 4; ci++) {
            int r_ = wc + ci * 16 + m16;
            b[ci] = *(const bfrag*)&Bs[c][r_ * 32 + (q ^ ((r_ >> 1) & 3)) * 8];
        }
#pragma unroll
        for (int ri = 0; ri < 4; ri++)
#pragma unroll
            for (int ci = 0; ci < 4; ci++)
                acc[ri][ci] = __builtin_amdgcn_mfma_f32_16x16x32_bf16(
                    a[ri], b[ci], acc[ri][ci], 0, 0, 0);
        __syncthreads();        // drains staged loads; loads flew over compute
        c ^= 1;
    }
#undef STAGE_T

    if (BF16OUT) {
        // In-register re/im pairing (verified R2/R3): shfl_xor(1) pairs cols.
        unsigned int* Cb = (unsigned int*)Co;
        const int colc0 = (col0 >> 1) + (w & 1) * 32;
#pragma unroll
        for (int ri = 0; ri < 4; ri++)
#pragma unroll
            for (int cp = 0; cp < 2; cp++)
#pragma unroll
                for (int r4 = 0; r4 < 4; r4++) {
                    float a0 = acc[ri][cp * 2][r4];
                    float a1 = acc[ri][cp * 2 + 1][r4];
                    float b0 = __shfl_xor(a0, 1);
                    float b1 = __shfl_xor(a1, 1);
                    unsigned int uo = (m16 & 1) ? pk2(b1, a1) : pk2(a0, b0);
                    int row = row0 + wr + ri * 16 + q * 4 + r4;
                    int ccol = (cp * 2 + (m16 & 1)) * 8 + (m16 >> 1);
                    Cb[(size_t)row * (ND / 2) + colc0 + ccol] = uo;
                }
    } else {
        // fp32 dword scatter: per (ri,r4,ci) 16 lanes = one full 64B line.
        float* Cf = (float*)Co;
#pragma unroll
        for (int ri = 0; ri < 4; ri++)
#pragma unroll
            for (int r4 = 0; r4 < 4; r4++) {
                int row = row0 + wr + ri * 16 + q * 4 + r4;
#pragma unroll
                for (int ci = 0; ci < 4; ci++) {
                    int col = col0 + wc + ci * 16 + m16;
                    Cf[(size_t)row * ND + col] = acc[ri][ci][r4];
                }
            }
    }
}

// ------- scan phase 1: chunk-final states (uint2 per lane, R6/R7-verified) --
__global__ __launch_bounds__(256) void scan_states_kernel(
    const unsigned int* __restrict__ bu, const float2* __restrict__ lam,
    float2* __restrict__ states)
{
    int t = threadIdx.x;
    int b = blockIdx.x >> 6;
    int c = blockIdx.x & 63;
    float4 lm = *(const float4*)&lam[2 * t];   // (l0.re,l0.im,l1.re,l1.im)
    float x0r = 0.f, x0i = 0.f, x1r = 0.f, x1i = 0.f;
    bool fwd = (t < 128);
    int l0 = fwd ? (c * CHUNK) : (c * CHUNK + CHUNK - 1);
    const unsigned int* p = bu + ((size_t)b * L_SEQ + l0) * 512 + 2 * t;
    ptrdiff_t step = fwd ? 512 : -512;
#pragma unroll 8
    for (int i = 0; i < CHUNK; i++) {
        uint2 v = *(const uint2*)p;
        float2 v0 = unpk2(v.x), v1 = unpk2(v.y);
        float n0r = lm.x * x0r - lm.y * x0i + v0.x;
        float n0i = lm.x * x0i + lm.y * x0r + v0.y;
        float n1r = lm.z * x1r - lm.w * x1i + v1.x;
        float n1i = lm.z * x1i + lm.w * x1r + v1.y;
        x0r = n0r; x0i = n0i; x1r = n1r; x1i = n1i;
        p += step;
    }
    *(float4*)&states[((size_t)b * NCHUNK + c) * 512 + 2 * t] =
        make_float4(x0r, x0i, x1r, x1i);
}

// ---- scan phase 2: combine chunk states -> exclusive carries ---------------
// 32 blocks x 64 threads (vs R2's 8 blocks): block = (b, n-slice of 128 n's);
// thread owns 2 complex n's (float4). Group-of-8 preload (R2-verified order:
// store exclusive carry THEN update). Serial c-chain ~2-3 us across 32 CUs.
__global__ __launch_bounds__(64) void scan_combine_kernel(
    const float2* __restrict__ states, float2* __restrict__ carries,
    const float2* __restrict__ lam)
{
    int b = blockIdx.x >> 2;                 // batch
    int s = blockIdx.x & 3;                  // n-slice
    int np = s * 64 + threadIdx.x;           // n-pair index in [0,256)
    int n0 = 2 * np;
    bool fwd = (s < 2);                      // n0 < 256  (block-uniform)
    float4 lm = *(const float4*)&lam[n0];

    // lam^64 per component (6 squarings)
    float a0r = lm.x, a0i = lm.y, a1r = lm.z, a1i = lm.w;
#pragma unroll
    for (int i = 0; i < 6; i++) {
        float n0r_ = a0r * a0r - a0i * a0i; a0i = 2.f * a0r * a0i; a0r = n0r_;
        float n1r_ = a1r * a1r - a1i * a1i; a1i = 2.f * a1r * a1i; a1r = n1r_;
    }

    float c0r = 0.f, c0i = 0.f, c1r = 0.f, c1i = 0.f;
    for (int g = 0; g < 8; ++g) {
        float4 st[8];
#pragma unroll
        for (int k = 0; k < 8; ++k) {
            int cc = fwd ? (g * 8 + k) : (63 - (g * 8 + k));
            st[k] = *(const float4*)&states[((size_t)b * NCHUNK + cc) * 512 + n0];
        }
#pragma unroll
        for (int k = 0; k < 8; ++k) {
            int cc = fwd ? (g * 8 + k) : (63 - (g * 8 + k));
            *(float4*)&carries[((size_t)b * NCHUNK + cc) * 512 + n0] =
                make_float4(c0r, c0i, c1r, c1i);
            float n0r_ = a0r * c0r - a0i * c0i + st[k].x;
            float n0i_ = a0r * c0i + a0i * c0r + st[k].y;
            float n1r_ = a1r * c1r - a1i * c1i + st[k].z;
            float n1i_ = a1r * c1i + a1i * c1r + st[k].w;
            c0r = n0r_; c0i = n0i_; c1r = n1r_; c1i = n1i_;
        }
    }
}

// -------- scan phase 3: rescan seeded with carry + mask (uint2/lane) --------
// Body harness-verified in R6 (standalone vectorized apply reading carries).
__global__ __launch_bounds__(256) void scan_apply_kernel(
    unsigned int* __restrict__ bu, const float2* __restrict__ carries,
    const float2* __restrict__ lam, const int* __restrict__ lengths)
{
    int t = threadIdx.x;
    int b = blockIdx.x >> 6;
    int c = blockIdx.x & 63;
    int len = lengths[b];
    float4 lm = *(const float4*)&lam[2 * t];
    float4 cy = *(const float4*)&carries[((size_t)b * NCHUNK + c) * 512 + 2 * t];
    bool fwd = (t < 128);
    int l0 = fwd ? (c * CHUNK) : (c * CHUNK + CHUNK - 1);
    int dl = fwd ? 1 : -1;
    unsigned int* p = bu + ((size_t)b * L_SEQ + l0) * 512 + 2 * t;
    ptrdiff_t step = fwd ? 512 : -512;
    float x0r = cy.x, x0i = cy.y, x1r = cy.z, x1i = cy.w;
    int l = l0;
#pragma unroll 8
    for (int i = 0; i < CHUNK; i++) {
        uint2 v = *(const uint2*)p;
        float2 v0 = unpk2(v.x), v1 = unpk2(v.y);
        float n0r = lm.x * x0r - lm.y * x0i + v0.x;
        float n0i = lm.x * x0i + lm.y * x0r + v0.y;
        float n1r = lm.z * x1r - lm.w * x1i + v1.x;
        float n1i = lm.z * x1i + lm.w * x1r + v1.y;
        x0r = n0r; x0i = n0i; x1r = n1r; x1i = n1i;
        uint2 o2;
        o2.x = (l >= len) ? 0u : pk2(x0r, x0i);
        o2.y = (l >= len) ? 0u : pk2(x1r, x1i);
        *(uint2*)p = o2;
        p += step; l += dl;
    }
}

// ---------------- launch ----------------------------------------------------
extern "C" void kernel_launch(void* const* d_in, const int* in_sizes, int n_in,
                              void* d_out, int out_size, void* d_ws, size_t ws_size,
                              hipStream_t stream)
{
    const float* u        = (const float*)d_in[0];   // (8,4096,512)
    const int*   lengths  = (const int*)  d_in[1];   // (8,)
    const float* nu_log   = (const float*)d_in[2];   // (512,)
    const float* theta_log= (const float*)d_in[3];   // (512,)
    const float* B        = (const float*)d_in[4];   // (512,512,2) == (512 x 1024)
    const float* C        = (const float*)d_in[5];   // (2,512,512)
    float* y = (float*)d_out;                        // (8,4096,512)

    char* wp = (char*)d_ws;
    float2* lam     = (float2*)wp;  wp += 4096;
    float2* states  = (float2*)wp;  wp += (size_t)BSZQ * NCHUNK * 512 * 8;  // 2 MB
    float2* carries = (float2*)wp;  wp += (size_t)BSZQ * NCHUNK * 512 * 8;  // 2 MB
    unsigned int* bu = (unsigned int*)wp; wp += (size_t)ROWS * 512 * 4;     // 64 MB packed bf16
    unsigned short* ub = (unsigned short*)wp; wp += (size_t)ROWS * 512 * 2; // 32 MB
    unsigned short* Bt = (unsigned short*)wp; wp += (size_t)NC1 * KC1 * 2;  // 1 MB
    unsigned short* Dt = (unsigned short*)wp; wp += (size_t)NC2 * KC2 * 2;  // 1 MB

    prep_conv_kernel<<<12289, 256, 0, stream>>>(
        u, lengths, B, C, nu_log, theta_log, ub, Bt, Dt, lam);

    // GEMM1: bu(packed bf16) = ub @ Bt^T  (mask folded into ub)
    {
        dim3 grid(ROWS / 128, NC1 / 128);   // (256, 8)
        gemm_db<KC1, NC1, true><<<grid, 256, 0, stream>>>(ub, Bt, bu);
    }

    scan_states_kernel<<<BSZQ * NCHUNK, 256, 0, stream>>>(bu, lam, states);
    scan_combine_kernel<<<BSZQ * 4, 64, 0, stream>>>(states, carries, lam);
    scan_apply_kernel<<<BSZQ * NCHUNK, 256, 0, stream>>>(bu, carries, lam, lengths);

    // GEMM2: y = bu(=x, packed bf16) @ Dt^T, fp32 out
    {
        dim3 grid(ROWS / 128, NC2 / 128);   // (256, 4)
        gemm_db<KC2, NC2, false><<<grid, 256, 0, stream>>>(
            (const unsigned short*)bu, Dt, y);
    }
}

// Round 10
// 255.963 us; speedup vs baseline: 1.1429x; 1.0280x over previous
//
#include <hip/hip_runtime.h>

// Problem constants
#define L_SEQ   4096
#define BSZQ    8
#define ROWS    (BSZQ * L_SEQ)      // 32768
#define KC1     512                 // GEMM1 K  (= H)
#define NC1     1024                // GEMM1 out cols (= 2*N interleaved re/im)
#define KC2     1024                // GEMM2 K
#define NC2     512                 // GEMM2 out cols (= H)
#define CHUNK   64
#define NCHUNK  64                  // L_SEQ / CHUNK

typedef __attribute__((ext_vector_type(8))) short bfrag;   // 8 bf16 (4 VGPRs)
typedef __attribute__((ext_vector_type(4))) float ffrag;   // 4 fp32 acc

static __device__ __forceinline__ unsigned short f2bf(float f) {
    union { float f; unsigned int u; } v; v.f = f;
    unsigned int r = v.u + 0x7fffu + ((v.u >> 16) & 1u);   // round-nearest-even
    return (unsigned short)(r >> 16);
}
static __device__ __forceinline__ unsigned int pk2(float a, float b) {
    return (unsigned int)f2bf(a) | ((unsigned int)f2bf(b) << 16);
}
static __device__ __forceinline__ float2 unpk2(unsigned int u) {
    union { unsigned int u; float f; } a, b;
    a.u = u << 16;
    b.u = u & 0xffff0000u;
    return make_float2(a.f, b.f);
}
static __device__ __forceinline__ float2 cmul(float2 a, float2 b) {
    return make_float2(a.x * b.x - a.y * b.y, a.x * b.y + a.y * b.x);
}

// async global->LDS, 16B per lane; lds dest = wave-uniform base + lane*16
static __device__ __forceinline__ void async16(const void* g, void* l) {
    __builtin_amdgcn_global_load_lds(
        (const __attribute__((address_space(1))) unsigned int*)g,
        (__attribute__((address_space(3))) unsigned int*)l,
        16, 0, 0);
}

// ---- fused prep + conv: conv_mask | Bt | Dt | lam (disjoint elementwise) ---
__global__ __launch_bounds__(256) void prep_conv_kernel(
    const float* __restrict__ u, const int* __restrict__ lengths,
    const float* __restrict__ B, const float* __restrict__ C,
    const float* __restrict__ nu_log, const float* __restrict__ theta_log,
    unsigned short* __restrict__ ub, unsigned short* __restrict__ Bt,
    unsigned short* __restrict__ Dt, float2* __restrict__ lam)
{
    int g = blockIdx.x, tid = threadIdx.x;
    if (g < 8192) {
        int idx = g * 256 + tid;                // 2,097,152 total (x8 elems)
        int row = idx >> 6;                     // flat row (b*L + l)
        int l = row & (L_SEQ - 1), b = row >> 12;
        bool keep = (l < lengths[b]);
        union { unsigned int s[4]; float4 f; } o;
        if (keep) {
            const float4 a = *(const float4*)(u + (size_t)idx * 8);
            const float4 c = *(const float4*)(u + (size_t)idx * 8 + 4);
            o.s[0] = pk2(a.x, a.y); o.s[1] = pk2(a.z, a.w);
            o.s[2] = pk2(c.x, c.y); o.s[3] = pk2(c.z, c.w);
        } else {
            o.s[0] = o.s[1] = o.s[2] = o.s[3] = 0u;
        }
        *(float4*)(ub + (size_t)idx * 8) = o.f;
    } else if (g < 10240) {
        int idx = (g - 8192) * 256 + tid;       // 524288 total
        int n2 = idx >> 9, h = idx & 511;
        Bt[idx] = f2bf(B[(size_t)h * 1024 + n2]);
    } else if (g < 12288) {
        int idx = (g - 10240) * 256 + tid;      // 524288 total
        int j = idx >> 10, k = idx & 1023;
        int n = k >> 1, c = k & 1;
        float v = C[((size_t)c * 512 + n) * 512 + j];
        Dt[idx] = f2bf(c ? -v : v);
    } else {
#pragma unroll
        for (int r = 0; r < 2; r++) {
            int n = tid + r * 256;
            float mag = expf(-expf(nu_log[n]));
            float th  = expf(theta_log[n]);
            lam[n] = make_float2(mag * cosf(th), mag * sinf(th));
        }
    }
}

// ============ 128x128 BK=32 double-buffered issue-early GEMM ================
// R3/R7-verified structure (53-55 us per dispatch): 4 waves (2x2), 64x64 per
// wave, 32 KB LDS -> 4 blocks/CU; issue-early staging + single __syncthreads
// per K-step; both-sides XOR swizzle (zero bank conflicts measured).
// NEW (BF16OUT only): fused chunk-state computation. A block's 128 rows are
// exactly 2 scan-chunks; each wave's wr-half is one chunk x 32 complex cols.
// Chunk-final state = weighted sum: fwd sum_r lam^(63-r) v_r, bwd sum_r
// lam^r v_r, with r = 16*ri + 4*q + r4 -> weight = A[ri-term]*B[q-term]*
// C[r4-term] from lam^16/lam^4/lam^1 power tables. Partial per lane over the
// pre-pack fp32 acc values, shfl_xor(16/32) reduce over q, q==0 lanes store.
// Eliminates the scan_states kernel (64 MB re-read of bu).
template<int KD, int ND, bool BF16OUT>
__global__ __launch_bounds__(256, 4) void gemm_db(
    const unsigned short* __restrict__ A,   // row-major [., KD] bf16
    const unsigned short* __restrict__ Bt,  // row-major [ND, KD] bf16
    void* __restrict__ Co,
    const float2* __restrict__ lamg,        // (BF16OUT) lam per complex col
    float2* __restrict__ states)            // (BF16OUT) [B][NCHUNK][512]
{
    __shared__ __align__(16) unsigned short As[2][128 * 32];  // 2 x 8 KB
    __shared__ __align__(16) unsigned short Bs[2][128 * 32];  // 2 x 8 KB

    const int tid  = threadIdx.x;
    const int lane = tid & 63, w = tid >> 6;
    const int q = lane >> 4, m16 = lane & 15;
    const int wr = (w >> 1) * 64, wc = (w & 1) * 64;
    const int row0 = blockIdx.x * 128;
    const int col0 = blockIdx.y * 128;

    ffrag acc[4][4];
#pragma unroll
    for (int i = 0; i < 4; i++)
#pragma unroll
        for (int j = 0; j < 4; j++) acc[i][j] = (ffrag)0.f;

    // Stage one 128x32 bf16 tile (8 KB = 512 x 16B slots) at K-offset KT.
#define STAGE_T(GP, TB, KT, GR0) do {                                          \
    _Pragma("unroll")                                                          \
    for (int j_ = 0; j_ < 2; j_++) {                                           \
        int s_ = j_ * 256 + tid;                                               \
        int r_ = s_ >> 2;                                                      \
        int cs_ = (s_ & 3) ^ ((r_ >> 1) & 3);                                  \
        async16(GP + (size_t)((GR0) + r_) * KD + (KT) + cs_ * 8,               \
                &TB[(size_t)(j_ * 256 + w * 64) * 8]);                         \
    }                                                                          \
} while (0)

    // prologue
    STAGE_T(A,  As[0], 0, row0);
    STAGE_T(Bt, Bs[0], 0, col0);
    __syncthreads();

    int c = 0;
    for (int kt = 0; kt < KD; kt += 32) {
        if (kt + 32 < KD) {                      // issue-early next tile
            STAGE_T(A,  As[c ^ 1], kt + 32, row0);
            STAGE_T(Bt, Bs[c ^ 1], kt + 32, col0);
        }
        bfrag a[4], b[4];
#pragma unroll
        for (int ri = 0; ri < 4; ri++) {
            int r_ = wr + ri * 16 + m16;
            a[ri] = *(const bfrag*)&As[c][r_ * 32 + (q ^ ((r_ >> 1) & 3)) * 8];
        }
#pragma unroll
        for (int ci = 0; ci < 4; ci++) {
            int r_ = wc + ci * 16 + m16;
            b[ci] = *(const bfrag*)&Bs[c][r_ * 32 + (q ^ ((r_ >> 1) & 3)) * 8];
        }
#pragma unroll
        for (int ri = 0; ri < 4; ri++)
#pragma unroll
            for (int ci = 0; ci < 4; ci++)
                acc[ri][ci] = __builtin_amdgcn_mfma_f32_16x16x32_bf16(
                    a[ri], b[ci], acc[ri][ci], 0, 0, 0);
        __syncthreads();        // drains staged loads; loads flew over compute
        c ^= 1;
    }
#undef STAGE_T

    if (BF16OUT) {
        unsigned int* Cb = (unsigned int*)Co;
        const int colc0 = (col0 >> 1) + (w & 1) * 32;
        const bool fwd = (col0 * 2 < ND);        // n < 256 half  (block-uniform)
        const int b_  = row0 >> 12;
        const int cch = ((row0 >> 6) & 63) + (wr >> 6);   // this wave's chunk
        const float2 one = make_float2(1.f, 0.f);
        float2 Ssum[2];
#pragma unroll
        for (int cp = 0; cp < 2; cp++) {
            const int ccol = (cp * 2 + (m16 & 1)) * 8 + (m16 >> 1);
            // lam power tables for this complex col
            float2 lm  = lamg[colc0 + ccol];
            float2 c2  = cmul(lm, lm),  c3  = cmul(c2, lm);
            float2 p4  = cmul(c2, c2),  p8  = cmul(p4, p4), p12 = cmul(p8, p4);
            float2 a16 = cmul(p8, p8),  a32 = cmul(a16, a16), a48 = cmul(a32, a16);
            int eq = fwd ? 3 - q : q;
            float2 Bq = (eq == 0) ? one : (eq == 1) ? p4 : (eq == 2) ? p8 : p12;
            float2 S = make_float2(0.f, 0.f);
#pragma unroll
            for (int ri = 0; ri < 4; ri++) {
                float2 T = make_float2(0.f, 0.f);
#pragma unroll
                for (int r4 = 0; r4 < 4; r4++) {
                    float a0 = acc[ri][cp * 2][r4];
                    float a1 = acc[ri][cp * 2 + 1][r4];
                    float b0 = __shfl_xor(a0, 1);
                    float b1 = __shfl_xor(a1, 1);
                    unsigned int uo = (m16 & 1) ? pk2(b1, a1) : pk2(a0, b0);
                    int row = row0 + wr + ri * 16 + q * 4 + r4;
                    Cb[(size_t)row * (ND / 2) + colc0 + ccol] = uo;
                    // weighted-state accumulation on pre-pack fp32 values
                    float2 v = (m16 & 1) ? make_float2(b1, a1)
                                         : make_float2(a0, b0);
                    float2 wv = fwd ? ((r4 == 3) ? one : (r4 == 2) ? lm
                                      : (r4 == 1) ? c2 : c3)
                                    : ((r4 == 0) ? one : (r4 == 1) ? lm
                                      : (r4 == 2) ? c2 : c3);
                    T.x += wv.x * v.x - wv.y * v.y;
                    T.y += wv.x * v.y + wv.y * v.x;
                }
                float2 wa = fwd ? ((ri == 3) ? one : (ri == 2) ? a16
                                  : (ri == 1) ? a32 : a48)
                                : ((ri == 0) ? one : (ri == 1) ? a16
                                  : (ri == 2) ? a32 : a48);
                float2 E = cmul(wa, Bq);
                S.x += E.x * T.x - E.y * T.y;
                S.y += E.x * T.y + E.y * T.x;
            }
            Ssum[cp] = S;
        }
        // reduce partial states over the 4 q-lanes (lane bits 4,5)
#pragma unroll
        for (int cp = 0; cp < 2; cp++) {
            Ssum[cp].x += __shfl_xor(Ssum[cp].x, 16);
            Ssum[cp].y += __shfl_xor(Ssum[cp].y, 16);
            Ssum[cp].x += __shfl_xor(Ssum[cp].x, 32);
            Ssum[cp].y += __shfl_xor(Ssum[cp].y, 32);
        }
        if (q == 0) {
#pragma unroll
            for (int cp = 0; cp < 2; cp++) {
                int ccol = (cp * 2 + (m16 & 1)) * 8 + (m16 >> 1);
                states[((size_t)b_ * NCHUNK + cch) * 512 + colc0 + ccol] =
                    Ssum[cp];
            }
        }
    } else {
        // fp32 dword scatter: per (ri,r4,ci) 16 lanes = one full 64B line.
        float* Cf = (float*)Co;
#pragma unroll
        for (int ri = 0; ri < 4; ri++)
#pragma unroll
            for (int r4 = 0; r4 < 4; r4++) {
                int row = row0 + wr + ri * 16 + q * 4 + r4;
#pragma unroll
                for (int ci = 0; ci < 4; ci++) {
                    int col = col0 + wc + ci * 16 + m16;
                    Cf[(size_t)row * ND + col] = acc[ri][ci][r4];
                }
            }
    }
}

// ---- scan phase 2: combine chunk states -> exclusive carries ---------------
// 32 blocks x 64 threads; thread owns 2 complex n's (float4). Group-of-8
// preload; store exclusive carry THEN update (R2-verified order).
__global__ __launch_bounds__(64) void scan_combine_kernel(
    const float2* __restrict__ states, float2* __restrict__ carries,
    const float2* __restrict__ lam)
{
    int b = blockIdx.x >> 2;                 // batch
    int s = blockIdx.x & 3;                  // n-slice
    int np = s * 64 + threadIdx.x;           // n-pair index in [0,256)
    int n0 = 2 * np;
    bool fwd = (s < 2);                      // n0 < 256  (block-uniform)
    float4 lm = *(const float4*)&lam[n0];

    // lam^64 per component (6 squarings)
    float a0r = lm.x, a0i = lm.y, a1r = lm.z, a1i = lm.w;
#pragma unroll
    for (int i = 0; i < 6; i++) {
        float n0r_ = a0r * a0r - a0i * a0i; a0i = 2.f * a0r * a0i; a0r = n0r_;
        float n1r_ = a1r * a1r - a1i * a1i; a1i = 2.f * a1r * a1i; a1r = n1r_;
    }

    float c0r = 0.f, c0i = 0.f, c1r = 0.f, c1i = 0.f;
    for (int g = 0; g < 8; ++g) {
        float4 st[8];
#pragma unroll
        for (int k = 0; k < 8; ++k) {
            int cc = fwd ? (g * 8 + k) : (63 - (g * 8 + k));
            st[k] = *(const float4*)&states[((size_t)b * NCHUNK + cc) * 512 + n0];
        }
#pragma unroll
        for (int k = 0; k < 8; ++k) {
            int cc = fwd ? (g * 8 + k) : (63 - (g * 8 + k));
            *(float4*)&carries[((size_t)b * NCHUNK + cc) * 512 + n0] =
                make_float4(c0r, c0i, c1r, c1i);
            float n0r_ = a0r * c0r - a0i * c0i + st[k].x;
            float n0i_ = a0r * c0i + a0i * c0r + st[k].y;
            float n1r_ = a1r * c1r - a1i * c1i + st[k].z;
            float n1i_ = a1r * c1i + a1i * c1r + st[k].w;
            c0r = n0r_; c0i = n0i_; c1r = n1r_; c1i = n1i_;
        }
    }
}

// -------- scan phase 3: rescan seeded with carry + mask (uint2/lane) --------
__global__ __launch_bounds__(256) void scan_apply_kernel(
    unsigned int* __restrict__ bu, const float2* __restrict__ carries,
    const float2* __restrict__ lam, const int* __restrict__ lengths)
{
    int t = threadIdx.x;
    int b = blockIdx.x >> 6;
    int c = blockIdx.x & 63;
    int len = lengths[b];
    float4 lm = *(const float4*)&lam[2 * t];
    float4 cy = *(const float4*)&carries[((size_t)b * NCHUNK + c) * 512 + 2 * t];
    bool fwd = (t < 128);
    int l0 = fwd ? (c * CHUNK) : (c * CHUNK + CHUNK - 1);
    int dl = fwd ? 1 : -1;
    unsigned int* p = bu + ((size_t)b * L_SEQ + l0) * 512 + 2 * t;
    ptrdiff_t step = fwd ? 512 : -512;
    float x0r = cy.x, x0i = cy.y, x1r = cy.z, x1i = cy.w;
    int l = l0;
#pragma unroll 8
    for (int i = 0; i < CHUNK; i++) {
        uint2 v = *(const uint2*)p;
        float2 v0 = unpk2(v.x), v1 = unpk2(v.y);
        float n0r = lm.x * x0r - lm.y * x0i + v0.x;
        float n0i = lm.x * x0i + lm.y * x0r + v0.y;
        float n1r = lm.z * x1r - lm.w * x1i + v1.x;
        float n1i = lm.z * x1i + lm.w * x1r + v1.y;
        x0r = n0r; x0i = n0i; x1r = n1r; x1i = n1i;
        uint2 o2;
        o2.x = (l >= len) ? 0u : pk2(x0r, x0i);
        o2.y = (l >= len) ? 0u : pk2(x1r, x1i);
        *(uint2*)p = o2;
        p += step; l += dl;
    }
}

// ---------------- launch ----------------------------------------------------
extern "C" void kernel_launch(void* const* d_in, const int* in_sizes, int n_in,
                              void* d_out, int out_size, void* d_ws, size_t ws_size,
                              hipStream_t stream)
{
    const float* u        = (const float*)d_in[0];   // (8,4096,512)
    const int*   lengths  = (const int*)  d_in[1];   // (8,)
    const float* nu_log   = (const float*)d_in[2];   // (512,)
    const float* theta_log= (const float*)d_in[3];   // (512,)
    const float* B        = (const float*)d_in[4];   // (512,512,2) == (512 x 1024)
    const float* C        = (const float*)d_in[5];   // (2,512,512)
    float* y = (float*)d_out;                        // (8,4096,512)

    char* wp = (char*)d_ws;
    float2* lam     = (float2*)wp;  wp += 4096;
    float2* states  = (float2*)wp;  wp += (size_t)BSZQ * NCHUNK * 512 * 8;  // 2 MB
    float2* carries = (float2*)wp;  wp += (size_t)BSZQ * NCHUNK * 512 * 8;  // 2 MB
    unsigned int* bu = (unsigned int*)wp; wp += (size_t)ROWS * 512 * 4;     // 64 MB packed bf16
    unsigned short* ub = (unsigned short*)wp; wp += (size_t)ROWS * 512 * 2; // 32 MB
    unsigned short* Bt = (unsigned short*)wp; wp += (size_t)NC1 * KC1 * 2;  // 1 MB
    unsigned short* Dt = (unsigned short*)wp; wp += (size_t)NC2 * KC2 * 2;  // 1 MB

    prep_conv_kernel<<<12289, 256, 0, stream>>>(
        u, lengths, B, C, nu_log, theta_log, ub, Bt, Dt, lam);

    // GEMM1: bu(packed bf16) = ub @ Bt^T  (+ fused chunk-state computation)
    {
        dim3 grid(ROWS / 128, NC1 / 128);   // (256, 8)
        gemm_db<KC1, NC1, true><<<grid, 256, 0, stream>>>(
            ub, Bt, bu, lam, states);
    }

    scan_combine_kernel<<<BSZQ * 4, 64, 0, stream>>>(states, carries, lam);
    scan_apply_kernel<<<BSZQ * NCHUNK, 256, 0, stream>>>(bu, carries, lam, lengths);

    // GEMM2: y = bu(=x, packed bf16) @ Dt^T, fp32 out
    {
        dim3 grid(ROWS / 128, NC2 / 128);   // (256, 4)
        gemm_db<KC2, NC2, false><<<grid, 256, 0, stream>>>(
            (const unsigned short*)bu, Dt, y, nullptr, nullptr);
    }
}

// Round 12
// 253.681 us; speedup vs baseline: 1.1532x; 1.0090x over previous
//
#include <hip/hip_runtime.h>

// Problem constants
#define L_SEQ   4096
#define BSZQ    8
#define ROWS    (BSZQ * L_SEQ)      // 32768
#define KC1     512                 // GEMM1 K  (= H)
#define NC1     1024                // GEMM1 out cols (= 2*N interleaved re/im)
#define KC2     1024                // GEMM2 K
#define NC2     512                 // GEMM2 out cols (= H)
#define CHUNK   64
#define NCHUNK  64                  // L_SEQ / CHUNK

typedef __attribute__((ext_vector_type(8))) short bfrag;   // 8 bf16 (4 VGPRs)
typedef __attribute__((ext_vector_type(4))) float ffrag;   // 4 fp32 acc

static __device__ __forceinline__ unsigned short f2bf(float f) {
    union { float f; unsigned int u; } v; v.f = f;
    unsigned int r = v.u + 0x7fffu + ((v.u >> 16) & 1u);   // round-nearest-even
    return (unsigned short)(r >> 16);
}
static __device__ __forceinline__ unsigned int pk2(float a, float b) {
    return (unsigned int)f2bf(a) | ((unsigned int)f2bf(b) << 16);
}
static __device__ __forceinline__ float2 unpk2(unsigned int u) {
    union { unsigned int u; float f; } a, b;
    a.u = u << 16;
    b.u = u & 0xffff0000u;
    return make_float2(a.f, b.f);
}
static __device__ __forceinline__ float2 cmul(float2 a, float2 b) {
    return make_float2(a.x * b.x - a.y * b.y, a.x * b.y + a.y * b.x);
}

// async global->LDS, 16B per lane; lds dest = wave-uniform base + lane*16
static __device__ __forceinline__ void async16(const void* g, void* l) {
    __builtin_amdgcn_global_load_lds(
        (const __attribute__((address_space(1))) unsigned int*)g,
        (__attribute__((address_space(3))) unsigned int*)l,
        16, 0, 0);
}

// ---- fused prep + conv: conv_mask | Bt | Dt | lam (disjoint elementwise) ---
__global__ __launch_bounds__(256) void prep_conv_kernel(
    const float* __restrict__ u, const int* __restrict__ lengths,
    const float* __restrict__ B, const float* __restrict__ C,
    const float* __restrict__ nu_log, const float* __restrict__ theta_log,
    unsigned short* __restrict__ ub, unsigned short* __restrict__ Bt,
    unsigned short* __restrict__ Dt, float2* __restrict__ lam)
{
    int g = blockIdx.x, tid = threadIdx.x;
    if (g < 8192) {
        int idx = g * 256 + tid;                // 2,097,152 total (x8 elems)
        int row = idx >> 6;                     // flat row (b*L + l)
        int l = row & (L_SEQ - 1), b = row >> 12;
        bool keep = (l < lengths[b]);
        union { unsigned int s[4]; float4 f; } o;
        if (keep) {
            const float4 a = *(const float4*)(u + (size_t)idx * 8);
            const float4 c = *(const float4*)(u + (size_t)idx * 8 + 4);
            o.s[0] = pk2(a.x, a.y); o.s[1] = pk2(a.z, a.w);
            o.s[2] = pk2(c.x, c.y); o.s[3] = pk2(c.z, c.w);
        } else {
            o.s[0] = o.s[1] = o.s[2] = o.s[3] = 0u;
        }
        *(float4*)(ub + (size_t)idx * 8) = o.f;
    } else if (g < 10240) {
        int idx = (g - 8192) * 256 + tid;       // 524288 total
        int n2 = idx >> 9, h = idx & 511;
        Bt[idx] = f2bf(B[(size_t)h * 1024 + n2]);
    } else if (g < 12288) {
        int idx = (g - 10240) * 256 + tid;      // 524288 total
        int j = idx >> 10, k = idx & 1023;
        int n = k >> 1, c = k & 1;
        float v = C[((size_t)c * 512 + n) * 512 + j];
        Dt[idx] = f2bf(c ? -v : v);
    } else {
#pragma unroll
        for (int r = 0; r < 2; r++) {
            int n = tid + r * 256;
            float mag = expf(-expf(nu_log[n]));
            float th  = expf(theta_log[n]);
            lam[n] = make_float2(mag * cosf(th), mag * sinf(th));
        }
    }
}

// ============ 128x128 BK=32 double-buffered issue-early GEMM ================
// R3/R7-verified structure. BF16OUT epilogue: R10's exact fused single-pass
// packed-store + chunk-state computation (R10-passing numerics, untouched).
// NEW (GEMM2 / !BF16OUT only): fully-masked block fast path — bu rows >= len
// are all-zero after scan_apply (both its paths write zeros there), so the
// slow path computed y=0; write y=0 directly and skip staging + K-loop.
// Output-identical by construction.
template<int KD, int ND, bool BF16OUT>
__global__ __launch_bounds__(256, 4) void gemm_db(
    const unsigned short* __restrict__ A,   // row-major [., KD] bf16
    const unsigned short* __restrict__ Bt,  // row-major [ND, KD] bf16
    void* __restrict__ Co,
    const float2* __restrict__ lamg,        // (BF16OUT) lam per complex col
    float2* __restrict__ states,            // (BF16OUT) [B][NCHUNK][512]
    const int* __restrict__ lengths)
{
    __shared__ __align__(16) unsigned short As[2][128 * 32];  // 2 x 8 KB
    __shared__ __align__(16) unsigned short Bs[2][128 * 32];  // 2 x 8 KB

    const int tid  = threadIdx.x;
    const int lane = tid & 63, w = tid >> 6;
    const int q = lane >> 4, m16 = lane & 15;
    const int wr = (w >> 1) * 64, wc = (w & 1) * 64;
    const int row0 = blockIdx.x * 128;
    const int col0 = blockIdx.y * 128;

    // ---- GEMM2-only fully-masked block fast path (block-uniform) ----
    if (!BF16OUT) {
        const int len_ = lengths[row0 >> 12];
        if ((row0 & (L_SEQ - 1)) >= len_) {
            float* Cf = (float*)Co;
#pragma unroll
            for (int ri = 0; ri < 4; ri++)
#pragma unroll
                for (int r4 = 0; r4 < 4; r4++) {
                    int row = row0 + wr + ri * 16 + q * 4 + r4;
#pragma unroll
                    for (int ci = 0; ci < 4; ci++)
                        Cf[(size_t)row * ND + col0 + wc + ci * 16 + m16] = 0.f;
                }
            return;
        }
    }

    ffrag acc[4][4];
#pragma unroll
    for (int i = 0; i < 4; i++)
#pragma unroll
        for (int j = 0; j < 4; j++) acc[i][j] = (ffrag)0.f;

    // Stage one 128x32 bf16 tile (8 KB = 512 x 16B slots) at K-offset KT.
#define STAGE_T(GP, TB, KT, GR0) do {                                          \
    _Pragma("unroll")                                                          \
    for (int j_ = 0; j_ < 2; j_++) {                                           \
        int s_ = j_ * 256 + tid;                                               \
        int r_ = s_ >> 2;                                                      \
        int cs_ = (s_ & 3) ^ ((r_ >> 1) & 3);                                  \
        async16(GP + (size_t)((GR0) + r_) * KD + (KT) + cs_ * 8,               \
                &TB[(size_t)(j_ * 256 + w * 64) * 8]);                         \
    }                                                                          \
} while (0)

    // prologue
    STAGE_T(A,  As[0], 0, row0);
    STAGE_T(Bt, Bs[0], 0, col0);
    __syncthreads();

    int c = 0;
    for (int kt = 0; kt < KD; kt += 32) {
        if (kt + 32 < KD) {                      // issue-early next tile
            STAGE_T(A,  As[c ^ 1], kt + 32, row0);
            STAGE_T(Bt, Bs[c ^ 1], kt + 32, col0);
        }
        bfrag a[4], b[4];
#pragma unroll
        for (int ri = 0; ri < 4; ri++) {
            int r_ = wr + ri * 16 + m16;
            a[ri] = *(const bfrag*)&As[c][r_ * 32 + (q ^ ((r_ >> 1) & 3)) * 8];
        }
#pragma unroll
        for (int ci = 0; ci < 4; ci++) {
            int r_ = wc + ci * 16 + m16;
            b[ci] = *(const bfrag*)&Bs[c][r_ * 32 + (q ^ ((r_ >> 1) & 3)) * 8];
        }
#pragma unroll
        for (int ri = 0; ri < 4; ri++)
#pragma unroll
            for (int ci = 0; ci < 4; ci++)
                acc[ri][ci] = __builtin_amdgcn_mfma_f32_16x16x32_bf16(
                    a[ri], b[ci], acc[ri][ci], 0, 0, 0);
        __syncthreads();        // drains staged loads; loads flew over compute
        c ^= 1;
    }
#undef STAGE_T

    if (BF16OUT) {
        // ---- R10's exact fused epilogue (passing numerics, untouched) ----
        unsigned int* Cb = (unsigned int*)Co;
        const int colc0 = (col0 >> 1) + (w & 1) * 32;
        const bool fwd = (col0 * 2 < ND);        // n < 256 half  (block-uniform)
        const int b_  = row0 >> 12;
        const int cch = ((row0 >> 6) & 63) + (wr >> 6);   // this wave's chunk
        const float2 one = make_float2(1.f, 0.f);
        float2 Ssum[2];
#pragma unroll
        for (int cp = 0; cp < 2; cp++) {
            const int ccol = (cp * 2 + (m16 & 1)) * 8 + (m16 >> 1);
            // lam power tables for this complex col
            float2 lm  = lamg[colc0 + ccol];
            float2 c2  = cmul(lm, lm),  c3  = cmul(c2, lm);
            float2 p4  = cmul(c2, c2),  p8  = cmul(p4, p4), p12 = cmul(p8, p4);
            float2 a16 = cmul(p8, p8),  a32 = cmul(a16, a16), a48 = cmul(a32, a16);
            int eq = fwd ? 3 - q : q;
            float2 Bq = (eq == 0) ? one : (eq == 1) ? p4 : (eq == 2) ? p8 : p12;
            float2 S = make_float2(0.f, 0.f);
#pragma unroll
            for (int ri = 0; ri < 4; ri++) {
                float2 T = make_float2(0.f, 0.f);
#pragma unroll
                for (int r4 = 0; r4 < 4; r4++) {
                    float a0 = acc[ri][cp * 2][r4];
                    float a1 = acc[ri][cp * 2 + 1][r4];
                    float b0 = __shfl_xor(a0, 1);
                    float b1 = __shfl_xor(a1, 1);
                    unsigned int uo = (m16 & 1) ? pk2(b1, a1) : pk2(a0, b0);
                    int row = row0 + wr + ri * 16 + q * 4 + r4;
                    Cb[(size_t)row * (ND / 2) + colc0 + ccol] = uo;
                    // weighted-state accumulation on pre-pack fp32 values
                    float2 v = (m16 & 1) ? make_float2(b1, a1)
                                         : make_float2(a0, b0);
                    float2 wv = fwd ? ((r4 == 3) ? one : (r4 == 2) ? lm
                                      : (r4 == 1) ? c2 : c3)
                                    : ((r4 == 0) ? one : (r4 == 1) ? lm
                                      : (r4 == 2) ? c2 : c3);
                    T.x += wv.x * v.x - wv.y * v.y;
                    T.y += wv.x * v.y + wv.y * v.x;
                }
                float2 wa = fwd ? ((ri == 3) ? one : (ri == 2) ? a16
                                  : (ri == 1) ? a32 : a48)
                                : ((ri == 0) ? one : (ri == 1) ? a16
                                  : (ri == 2) ? a32 : a48);
                float2 E = cmul(wa, Bq);
                S.x += E.x * T.x - E.y * T.y;
                S.y += E.x * T.y + E.y * T.x;
            }
            Ssum[cp] = S;
        }
        // reduce partial states over the 4 q-lanes (lane bits 4,5)
#pragma unroll
        for (int cp = 0; cp < 2; cp++) {
            Ssum[cp].x += __shfl_xor(Ssum[cp].x, 16);
            Ssum[cp].y += __shfl_xor(Ssum[cp].y, 16);
            Ssum[cp].x += __shfl_xor(Ssum[cp].x, 32);
            Ssum[cp].y += __shfl_xor(Ssum[cp].y, 32);
        }
        if (q == 0) {
#pragma unroll
            for (int cp = 0; cp < 2; cp++) {
                int ccol = (cp * 2 + (m16 & 1)) * 8 + (m16 >> 1);
                states[((size_t)b_ * NCHUNK + cch) * 512 + colc0 + ccol] =
                    Ssum[cp];
            }
        }
    } else {
        // fp32 dword scatter: per (ri,r4,ci) 16 lanes = one full 64B line.
        float* Cf = (float*)Co;
#pragma unroll
        for (int ri = 0; ri < 4; ri++)
#pragma unroll
            for (int r4 = 0; r4 < 4; r4++) {
                int row = row0 + wr + ri * 16 + q * 4 + r4;
#pragma unroll
                for (int ci = 0; ci < 4; ci++) {
                    int col = col0 + wc + ci * 16 + m16;
                    Cf[(size_t)row * ND + col] = acc[ri][ci][r4];
                }
            }
    }
}

// ---- scan phase 2: combine chunk states -> exclusive carries ---------------
// 32 blocks x 64 threads; thread owns 2 complex n's (float4). Group-of-8
// preload; store exclusive carry THEN update (R2-verified order).
__global__ __launch_bounds__(64) void scan_combine_kernel(
    const float2* __restrict__ states, float2* __restrict__ carries,
    const float2* __restrict__ lam)
{
    int b = blockIdx.x >> 2;                 // batch
    int s = blockIdx.x & 3;                  // n-slice
    int np = s * 64 + threadIdx.x;           // n-pair index in [0,256)
    int n0 = 2 * np;
    bool fwd = (s < 2);                      // n0 < 256  (block-uniform)
    float4 lm = *(const float4*)&lam[n0];

    // lam^64 per component (6 squarings)
    float a0r = lm.x, a0i = lm.y, a1r = lm.z, a1i = lm.w;
#pragma unroll
    for (int i = 0; i < 6; i++) {
        float n0r_ = a0r * a0r - a0i * a0i; a0i = 2.f * a0r * a0i; a0r = n0r_;
        float n1r_ = a1r * a1r - a1i * a1i; a1i = 2.f * a1r * a1i; a1r = n1r_;
    }

    float c0r = 0.f, c0i = 0.f, c1r = 0.f, c1i = 0.f;
    for (int g = 0; g < 8; ++g) {
        float4 st[8];
#pragma unroll
        for (int k = 0; k < 8; ++k) {
            int cc = fwd ? (g * 8 + k) : (63 - (g * 8 + k));
            st[k] = *(const float4*)&states[((size_t)b * NCHUNK + cc) * 512 + n0];
        }
#pragma unroll
        for (int k = 0; k < 8; ++k) {
            int cc = fwd ? (g * 8 + k) : (63 - (g * 8 + k));
            *(float4*)&carries[((size_t)b * NCHUNK + cc) * 512 + n0] =
                make_float4(c0r, c0i, c1r, c1i);
            float n0r_ = a0r * c0r - a0i * c0i + st[k].x;
            float n0i_ = a0r * c0i + a0i * c0r + st[k].y;
            float n1r_ = a1r * c1r - a1i * c1i + st[k].z;
            float n1i_ = a1r * c1i + a1i * c1r + st[k].w;
            c0r = n0r_; c0i = n0i_; c1r = n1r_; c1i = n1i_;
        }
    }
}

// -------- scan phase 3: rescan seeded with carry + mask (uint2/lane) --------
// Fully-masked chunk fast path (c*64 >= len): slow path would read bu and
// mask every store to zero; write the zeros directly (output-identical).
__global__ __launch_bounds__(256) void scan_apply_kernel(
    unsigned int* __restrict__ bu, const float2* __restrict__ carries,
    const float2* __restrict__ lam, const int* __restrict__ lengths)
{
    int t = threadIdx.x;
    int b = blockIdx.x >> 6;
    int c = blockIdx.x & 63;
    int len = lengths[b];

    if (c * CHUNK >= len) {                  // fully masked: x = 0
        unsigned int* p = bu + ((size_t)b * L_SEQ + c * CHUNK) * 512 + 2 * t;
#pragma unroll 8
        for (int i = 0; i < CHUNK; i++) {
            *(uint2*)p = make_uint2(0u, 0u);
            p += 512;
        }
        return;
    }

    float4 lm = *(const float4*)&lam[2 * t];
    float4 cy = *(const float4*)&carries[((size_t)b * NCHUNK + c) * 512 + 2 * t];
    bool fwd = (t < 128);
    int l0 = fwd ? (c * CHUNK) : (c * CHUNK + CHUNK - 1);
    int dl = fwd ? 1 : -1;
    unsigned int* p = bu + ((size_t)b * L_SEQ + l0) * 512 + 2 * t;
    ptrdiff_t step = fwd ? 512 : -512;
    float x0r = cy.x, x0i = cy.y, x1r = cy.z, x1i = cy.w;
    int l = l0;
#pragma unroll 8
    for (int i = 0; i < CHUNK; i++) {
        uint2 v = *(const uint2*)p;
        float2 v0 = unpk2(v.x), v1 = unpk2(v.y);
        float n0r = lm.x * x0r - lm.y * x0i + v0.x;
        float n0i = lm.x * x0i + lm.y * x0r + v0.y;
        float n1r = lm.z * x1r - lm.w * x1i + v1.x;
        float n1i = lm.z * x1i + lm.w * x1r + v1.y;
        x0r = n0r; x0i = n0i; x1r = n1r; x1i = n1i;
        uint2 o2;
        o2.x = (l >= len) ? 0u : pk2(x0r, x0i);
        o2.y = (l >= len) ? 0u : pk2(x1r, x1i);
        *(uint2*)p = o2;
        p += step; l += dl;
    }
}

// ---------------- launch ----------------------------------------------------
extern "C" void kernel_launch(void* const* d_in, const int* in_sizes, int n_in,
                              void* d_out, int out_size, void* d_ws, size_t ws_size,
                              hipStream_t stream)
{
    const float* u        = (const float*)d_in[0];   // (8,4096,512)
    const int*   lengths  = (const int*)  d_in[1];   // (8,)
    const float* nu_log   = (const float*)d_in[2];   // (512,)
    const float* theta_log= (const float*)d_in[3];   // (512,)
    const float* B        = (const float*)d_in[4];   // (512,512,2) == (512 x 1024)
    const float* C        = (const float*)d_in[5];   // (2,512,512)
    float* y = (float*)d_out;                        // (8,4096,512)

    char* wp = (char*)d_ws;
    float2* lam     = (float2*)wp;  wp += 4096;
    float2* states  = (float2*)wp;  wp += (size_t)BSZQ * NCHUNK * 512 * 8;  // 2 MB
    float2* carries = (float2*)wp;  wp += (size_t)BSZQ * NCHUNK * 512 * 8;  // 2 MB
    unsigned int* bu = (unsigned int*)wp; wp += (size_t)ROWS * 512 * 4;     // 64 MB packed bf16
    unsigned short* ub = (unsigned short*)wp; wp += (size_t)ROWS * 512 * 2; // 32 MB
    unsigned short* Bt = (unsigned short*)wp; wp += (size_t)NC1 * KC1 * 2;  // 1 MB
    unsigned short* Dt = (unsigned short*)wp; wp += (size_t)NC2 * KC2 * 2;  // 1 MB

    prep_conv_kernel<<<12289, 256, 0, stream>>>(
        u, lengths, B, C, nu_log, theta_log, ub, Bt, Dt, lam);

    // GEMM1: bu(packed bf16) = ub @ Bt^T  (+ fused chunk-state computation,
    // R10 exact path — no masking changes)
    {
        dim3 grid(ROWS / 128, NC1 / 128);   // (256, 8)
        gemm_db<KC1, NC1, true><<<grid, 256, 0, stream>>>(
            ub, Bt, bu, lam, states, lengths);
    }

    scan_combine_kernel<<<BSZQ * 4, 64, 0, stream>>>(states, carries, lam);
    scan_apply_kernel<<<BSZQ * NCHUNK, 256, 0, stream>>>(bu, carries, lam, lengths);

    // GEMM2: y = bu(=x, packed bf16) @ Dt^T, fp32 out (masked fast path)
    {
        dim3 grid(ROWS / 128, NC2 / 128);   // (256, 4)
        gemm_db<KC2, NC2, false><<<grid, 256, 0, stream>>>(
            (const unsigned short*)bu, Dt, y, nullptr, nullptr, lengths);
    }
}